// Round 9
// baseline (2913.822 us; speedup 1.0000x reference)
//
#include <hip/hip_runtime.h>

// ---------------------------------------------------------------------------
// <psi|U^dag O U|psi>, NQ=8, r=64 d=16 rl=16 ro=4.
// R9 = R8 + restructured gemm_g45 phase B:
//   phase A (G4) unchanged; t4 handoff via per-mt 256-k LDS slabs
//   slab[M2=16][k=256] (pad 264, k-innermost -> bf16x8 vector reads, 2-way
//   conflicts only). LDS 78->27 KB => 5 blocks/CU (was 2). Phase B = 4 x
//   (write slab, sync, 8 k-chunks x 3 MFMA). Everything else identical to R8.
// Formats:
//   env  fp32 [a·64][n=(l,o,m2,b)·65536]
//   t1   u32  [k=(l,i)·256][n=(o,m2,a4,b)·65536]  (bf16 hi|lo<<16)
//   t2   fp32 [k=(o,j)·64][n=(L,m2,a4,b)·262144]
//   t3   u32  [k=(m2,k2)·256][n=(O2,L,a4,b)·65536]
// ---------------------------------------------------------------------------

typedef __attribute__((ext_vector_type(8))) short bf16x8;
typedef __attribute__((ext_vector_type(4))) float f32x4;
typedef __attribute__((ext_vector_type(4))) unsigned short us4;

static __device__ __forceinline__ unsigned short f2bf(float x) {
    union { float f; unsigned u; } a; a.f = x;
    return (unsigned short)((a.u + 0x7FFF + ((a.u >> 16) & 1)) >> 16);
}
static __device__ __forceinline__ float bf2f(unsigned short h) {
    union { unsigned u; float f; } a; a.u = (unsigned)h << 16; return a.f;
}
static __device__ __forceinline__ unsigned split2(float x) {
    unsigned short h = f2bf(x);
    unsigned short l = f2bf(x - bf2f(h));
    return (unsigned)h | ((unsigned)l << 16);
}

__global__ void write_diag_kernel(float* out, float v) {
    if (threadIdx.x == 0 && blockIdx.x == 0) out[0] = v;
}
__global__ void zero_out(float* o) {
    if (threadIdx.x == 0 && blockIdx.x == 0) o[0] = 0.0f;
}

// ---- A-operand fragment packs -------------------------------------------
// Pack layout: [(k0*MT+mt)*2+hl][lane(64)][8]; frag k = k0*32+quad*8+j,
// m = mt*16 + (lane&15).

// G2 (Ud, k=(l,i), m=(j,L)) / G4 (U, k=(m2,k2), m=(s,M2)); MT=16, KT=8
__global__ void prep_apack(const float* __restrict__ layer,
                           unsigned short* __restrict__ Ap2,
                           unsigned short* __restrict__ Ap4) {
    int idx = blockIdx.x * 256 + threadIdx.x;   // 65536
    int q = idx >> 13, k0 = (idx >> 10) & 7, mt = (idx >> 6) & 15, lane = idx & 63;
    int quad = lane >> 4, r = lane & 15;
    unsigned short h2[8], l2[8], h4[8], l4[8];
#pragma unroll
    for (int j = 0; j < 8; j++) {
        int k = k0 * 32 + quad * 8 + j;
        int m = mt * 16 + r;
        float v2 = layer[(size_t)q * 65536 +
                         (size_t)((((k >> 4) * 16 + (m >> 4)) * 16 + (k & 15)) * 16 + (m & 15))];
        float v4 = layer[(size_t)q * 65536 +
                         (size_t)((((k >> 4) * 16 + (k & 15)) * 16 + (m >> 4)) * 16 + (m & 15))];
        h2[j] = f2bf(v2); l2[j] = f2bf(v2 - bf2f(h2[j]));
        h4[j] = f2bf(v4); l4[j] = f2bf(v4 - bf2f(h4[j]));
    }
    size_t base = ((size_t)((q * 8 + k0) * 16 + mt) * 2) * 512 + lane * 8;
    *(us4*)(Ap2 + base)       = *(us4*)&h2[0];
    *(us4*)(Ap2 + base + 4)   = *(us4*)&h2[4];
    *(us4*)(Ap2 + base + 512) = *(us4*)&l2[0];
    *(us4*)(Ap2 + base + 516) = *(us4*)&l2[4];
    *(us4*)(Ap4 + base)       = *(us4*)&h4[0];
    *(us4*)(Ap4 + base + 4)   = *(us4*)&h4[4];
    *(us4*)(Ap4 + base + 512) = *(us4*)&l4[0];
    *(us4*)(Ap4 + base + 516) = *(us4*)&l4[4];
}

// G1 (S as A): Amat[k=a][m=(i,a4)] = state[q][a][i][c*16+a4]; MT=16, KT=2
__global__ void prep_spack1(const float* __restrict__ state,
                            unsigned short* __restrict__ Sp1) {
    int idx = blockIdx.x * 256 + threadIdx.x;   // 65536
    int q = idx >> 13, c = (idx >> 11) & 3, k0 = (idx >> 10) & 1,
        mt = (idx >> 6) & 15, lane = idx & 63;
    int quad = lane >> 4, lr = lane & 15;
    unsigned short h[8], l[8];
#pragma unroll
    for (int j = 0; j < 8; j++) {
        int k = k0 * 32 + quad * 8 + j;
        float v = state[(size_t)q * 65536 + (size_t)(k * 16 + mt) * 64 + c * 16 + lr];
        h[j] = f2bf(v); l[j] = f2bf(v - bf2f(h[j]));
    }
    size_t base = (size_t)(q * 4 + c) * 32768 + ((size_t)(k0 * 16 + mt) * 2) * 512 + lane * 8;
    *(us4*)(Sp1 + base)       = *(us4*)&h[0];
    *(us4*)(Sp1 + base + 4)   = *(us4*)&h[4];
    *(us4*)(Sp1 + base + 512) = *(us4*)&l[0];
    *(us4*)(Sp1 + base + 516) = *(us4*)&l[4];
}

// G5 (S): frag[k=(s,b)=s*64+b][col=B'] = state[q][b][s][B']; MT=4, KT=32
__global__ void prep_spack5(const float* __restrict__ state,
                            unsigned short* __restrict__ Sp5) {
    int idx = blockIdx.x * 256 + threadIdx.x;   // 65536
    int q = idx >> 13, k0 = (idx >> 8) & 31, mt = (idx >> 6) & 3, lane = idx & 63;
    int quad = lane >> 4, lr = lane & 15;
    unsigned short h[8], l[8];
#pragma unroll
    for (int j = 0; j < 8; j++) {
        int k = k0 * 32 + quad * 8 + j;   // k = s*64+b
        int s = k >> 6, b = k & 63;
        float v = state[(size_t)q * 65536 + (size_t)(b * 16 + s) * 64 + mt * 16 + lr];
        h[j] = f2bf(v); l[j] = f2bf(v - bf2f(h[j]));
    }
    size_t base = (size_t)q * 131072 + ((size_t)(k0 * 4 + mt) * 2) * 512 + lane * 8;
    *(us4*)(Sp5 + base)       = *(us4*)&h[0];
    *(us4*)(Sp5 + base + 4)   = *(us4*)&h[4];
    *(us4*)(Sp5 + base + 512) = *(us4*)&l[0];
    *(us4*)(Sp5 + base + 516) = *(us4*)&l[4];
}

// G3 (O as A): Amat[k=(o,j2)][m=(k2,O2)] = oper[q][o][j2][k2][O2]; MT=4, KT=2
__global__ void prep_opack3(const float* __restrict__ oper,
                            unsigned short* __restrict__ Op3) {
    int idx = blockIdx.x * 256 + threadIdx.x;   // 4096
    int q = idx >> 9, k0 = (idx >> 8) & 1, mt = (idx >> 6) & 3, lane = idx & 63;
    int quad = lane >> 4, lr = lane & 15;
    unsigned short h[8], l[8];
#pragma unroll
    for (int j = 0; j < 8; j++) {
        int k = k0 * 32 + quad * 8 + j;
        int m = mt * 16 + lr;
        float v = oper[(size_t)q * 4096 + (size_t)(k * 16 + (m >> 2)) * 4 + (m & 3)];
        h[j] = f2bf(v); l[j] = f2bf(v - bf2f(h[j]));
    }
    size_t base = (size_t)q * 8192 + ((size_t)(k0 * 4 + mt) * 2) * 512 + lane * 8;
    *(us4*)(Op3 + base)       = *(us4*)&h[0];
    *(us4*)(Op3 + base + 4)   = *(us4*)&h[4];
    *(us4*)(Op3 + base + 512) = *(us4*)&l[0];
    *(us4*)(Op3 + base + 516) = *(us4*)&l[4];
}

// ---- site 0 (env0 = delta): env1 built by a cheap chain (fp32 exact) ----
__global__ void s0_g2(const float* __restrict__ state, const float* __restrict__ layer,
                      float* __restrict__ g2) {
    int t = blockIdx.x * 256 + threadIdx.x;          // 16384: [A][j][L]
    int A = t >> 8, j = (t >> 4) & 15, L = t & 15;
    float s = 0;
    for (int i = 0; i < 16; i++) s += state[i * 64 + A] * layer[(j * 16 + i) * 16 + L];
    g2[t] = s;
}
__global__ void s0_g3(const float* __restrict__ g2, const float* __restrict__ oper,
                      float* __restrict__ g3) {
    int t = blockIdx.x * 256 + threadIdx.x;          // 65536: [A][L][k][O]
    int A = t >> 10, L = (t >> 6) & 15, k = (t >> 2) & 15, O = t & 3;
    float s = 0;
    for (int j = 0; j < 16; j++) s += g2[A * 256 + j * 16 + L] * oper[(j * 16 + k) * 4 + O];
    g3[t] = s;
}
__global__ void s0_g4(const float* __restrict__ g3, const float* __restrict__ layer,
                      float* __restrict__ g4) {
    int t = blockIdx.x * 256 + threadIdx.x;          // 1048576: [A][L][O][s][M]
    int A = t >> 14, L = (t >> 10) & 15, O = (t >> 8) & 3, sp = (t >> 4) & 15, M = t & 15;
    float s = 0;
    for (int k = 0; k < 16; k++)
        s += g3[A * 1024 + L * 64 + k * 4 + O] * layer[(k * 16 + sp) * 16 + M];
    g4[t] = s;
}
__global__ void s0_env(const float* __restrict__ g4, const float* __restrict__ state,
                       float* __restrict__ env) {
    int t = blockIdx.x * 256 + threadIdx.x;          // 4194304: [A][L][O][M][B]
    int A = t >> 16, L = (t >> 12) & 15, O = (t >> 10) & 3, M = (t >> 6) & 15, B = t & 63;
    float s = 0;
    for (int sp = 0; sp < 16; sp++)
        s += g4[A * 16384 + L * 1024 + O * 256 + sp * 16 + M] * state[sp * 64 + B];
    env[t] = s;
}

// ---- site 7 chain (fp32) + fused dot ------------------------------------
__global__ void s7_c1(const float* __restrict__ state, const float* __restrict__ layer,
                      float* __restrict__ c1) {
    int t = blockIdx.x * 256 + threadIdx.x;          // 16384: [l][a][j]
    int l = t >> 10, a = (t >> 4) & 63, j = t & 15;
    float s = 0;
    for (int i = 0; i < 16; i++)
        s += state[7 * 65536 + (a * 16 + i) * 64] * layer[7 * 65536 + ((l * 16 + j) * 16 + i) * 16];
    c1[t] = s;
}
__global__ void s7_c2(const float* __restrict__ c1, const float* __restrict__ oper,
                      float* __restrict__ c2) {
    int t = blockIdx.x * 256 + threadIdx.x;          // 65536: [o][l][a][k]
    int o = t >> 14, l = (t >> 10) & 15, a = (t >> 4) & 63, k = t & 15;
    float s = 0;
    for (int j = 0; j < 16; j++)
        s += c1[l * 1024 + a * 16 + j] * oper[7 * 4096 + ((o * 16 + j) * 16 + k) * 4];
    c2[t] = s;
}
__global__ void s7_c3(const float* __restrict__ c2, const float* __restrict__ layer,
                      float* __restrict__ c3) {
    int t = blockIdx.x * 256 + threadIdx.x;          // 1048576: [m][o][l][a][s]
    int m = t >> 16, o = (t >> 14) & 3, l = (t >> 10) & 15, a = (t >> 4) & 63, sp = t & 15;
    float s = 0;
    for (int k = 0; k < 16; k++)
        s += c2[o * 16384 + l * 1024 + a * 16 + k] *
             layer[7 * 65536 + ((m * 16 + k) * 16 + sp) * 16];
    c3[t] = s;
}
__global__ void prep_sv(const float* __restrict__ state, float* __restrict__ sv) {
    int t = blockIdx.x * 256 + threadIdx.x;          // 1024: [b][sp]
    sv[t] = state[7 * 65536 + t * 64];
}
__global__ __launch_bounds__(256) void s7_fused(const float* __restrict__ env,
                                                const float* __restrict__ c3,
                                                const float* __restrict__ sv,
                                                float* __restrict__ out) {
    __shared__ float c3s[1024], svs[1024], red[256];
    int t = threadIdx.x;
    int n0 = blockIdx.x * 64;            // 1024 blocks; n=(l,o,m,b)
    int l = n0 >> 12, o = (n0 >> 10) & 3, m = (n0 >> 6) & 15;
    const float* c3b = c3 + m * 65536 + o * 16384 + l * 1024;   // [a][sp]
    for (int i = t; i < 1024; i += 256) { c3s[i] = c3b[i]; svs[i] = sv[i]; }
    __syncthreads();
    float s = 0;
    int b = t & 63, ag = t >> 6;
#pragma unroll
    for (int g = 0; g < 16; g++) {
        int a = ag * 16 + g;
        float e = env[(size_t)a * 65536 + n0 + b];   // row-major
        float w = 0;
#pragma unroll
        for (int sp = 0; sp < 16; sp++) w += c3s[a * 16 + sp] * svs[b * 16 + sp];
        s += e * w;
    }
    red[t] = s; __syncthreads();
    for (int off = 128; off; off >>= 1) { if (t < off) red[t] += red[t + off]; __syncthreads(); }
    if (t == 0) atomicAdd(out, red[0]);
}

// ---- unified bf16x3 MFMA GEMM (G1 / G2 / G3) -----------------------------
template <int KT, int MT, int WS, int BFMT, int SM>
__global__ __launch_bounds__(256) void gemm_u(const void* __restrict__ Bv,
                                              const unsigned short* __restrict__ Ap,
                                              float* __restrict__ Cf,
                                              unsigned* __restrict__ Cu,
                                              int Nfull) {
    constexpr int NT = (WS == 0) ? 4 : 1;
    __shared__ unsigned short Bs_h[64 * 40];
    __shared__ unsigned short Bs_l[64 * 40];
    const int tid = threadIdx.x, lane = tid & 63, wave = tid >> 6;
    const int quad = lane >> 4, lr = lane & 15;
    const int n0 = blockIdx.x * 64;
    const int snn = tid & 63, skg = tid >> 6;

    f32x4 acc[4][NT];
#pragma unroll
    for (int i = 0; i < 4; i++)
#pragma unroll
        for (int j = 0; j < NT; j++)
#pragma unroll
            for (int r = 0; r < 4; r++) acc[i][j][r] = 0.0f;

    unsigned ub[2][4];
    float    fb[2][4];

    auto load_tile = [&](int k0) {
        if constexpr (BFMT == 0) {
            const unsigned* Bp = (const unsigned*)Bv;
#pragma unroll
            for (int v = 0; v < 2; v++)
#pragma unroll
                for (int i = 0; i < 4; i++) {
                    int kk = (v * 4 + skg) * 4 + i;
                    ub[v][i] = Bp[(size_t)(k0 * 32 + kk) * Nfull + n0 + snn];
                }
        } else {
            const float* Bf = (const float*)Bv;
#pragma unroll
            for (int v = 0; v < 2; v++)
#pragma unroll
                for (int i = 0; i < 4; i++) {
                    int kk = (v * 4 + skg) * 4 + i;
                    fb[v][i] = Bf[(size_t)(k0 * 32 + kk) * Nfull + n0 + snn];
                }
        }
    };
    auto store_tile = [&]() {
#pragma unroll
        for (int v = 0; v < 2; v++) {
            us4 hv, lv;
#pragma unroll
            for (int i = 0; i < 4; i++) {
                unsigned s;
                if constexpr (BFMT == 0) s = ub[v][i];
                else                     s = split2(fb[v][i]);
                hv[i] = (unsigned short)s;
                lv[i] = (unsigned short)(s >> 16);
            }
            int base = snn * 40 + (v * 4 + skg) * 4;
            *(us4*)(&Bs_h[base]) = hv;
            *(us4*)(&Bs_l[base]) = lv;
        }
    };

    load_tile(0);
    store_tile();
    for (int k0 = 0; k0 < KT; k0++) {
        __syncthreads();
        if (k0 + 1 < KT) load_tile(k0 + 1);
        bf16x8 ah[4], al[4];
#pragma unroll
        for (int mt = 0; mt < 4; mt++) {
            int gmt = (WS == 0) ? (wave * 4 + mt) : mt;
            const unsigned short* ap = Ap + ((size_t)(k0 * MT + gmt) * 2) * 512 + lane * 8;
            ah[mt] = *(const bf16x8*)ap;
            al[mt] = *(const bf16x8*)(ap + 512);
        }
#pragma unroll
        for (int nt = 0; nt < NT; nt++) {
            int nl = (WS == 0) ? (nt * 16 + lr) : (wave * 16 + lr);
            bf16x8 bh = *(bf16x8*)(&Bs_h[nl * 40 + quad * 8]);
            bf16x8 bl = *(bf16x8*)(&Bs_l[nl * 40 + quad * 8]);
#pragma unroll
            for (int mt = 0; mt < 4; mt++) {
                acc[mt][nt] = __builtin_amdgcn_mfma_f32_16x16x32_bf16(ah[mt], bh, acc[mt][nt], 0, 0, 0);
                acc[mt][nt] = __builtin_amdgcn_mfma_f32_16x16x32_bf16(ah[mt], bl, acc[mt][nt], 0, 0, 0);
                acc[mt][nt] = __builtin_amdgcn_mfma_f32_16x16x32_bf16(al[mt], bh, acc[mt][nt], 0, 0, 0);
            }
        }
        __syncthreads();
        if (k0 + 1 < KT) store_tile();
    }

#pragma unroll
    for (int mt = 0; mt < 4; mt++) {
        int gmt = (WS == 0) ? (wave * 4 + mt) : mt;
#pragma unroll
        for (int nt = 0; nt < NT; nt++) {
            int n = n0 + ((WS == 0) ? nt * 16 : wave * 16) + lr;
#pragma unroll
            for (int r = 0; r < 4; r++) {
                int m = gmt * 16 + quad * 4 + r;
                float val = acc[mt][nt][r];
                if constexpr (SM == 1) {
                    int l = n >> 12, o = (n >> 10) & 3, m2 = (n >> 6) & 15, b = n & 63;
                    Cu[(size_t)(l * 16 + (m >> 4)) * 65536 +
                       o * 16384 + m2 * 1024 + (m & 15) * 64 + b] = split2(val);
                } else if constexpr (SM == 2) {
                    Cf[(size_t)((n >> 14) * 16 + (m >> 4)) * 262144 +
                       (m & 15) * 16384 + (n & 16383)] = val;
                } else {
                    int L = n >> 14, m2 = (n >> 10) & 15;
                    Cu[(size_t)(m2 * 16 + (m >> 2)) * 65536 +
                       (m & 3) * 16384 + L * 1024 + (n & 1023)] = split2(val);
                }
            }
        }
    }
}

// ---- fused G4+G5 (slab-interleaved phase B) ------------------------------
// Phase A: G4 on t3 n-strip (O2,L,a4 fixed, b=64), m=(s,M2). Phase B: per
// mt, all waves deposit slab[M2][k=256] (s = wave*4+mt, k-local = wave*64+b;
// pad 264 => 16B-aligned bf16x8 reads) then contract 8 k-chunks x 3 MFMA.
// LDS 27 KB => ~5 blocks/CU.
__global__ __launch_bounds__(256) void gemm_g45(const unsigned* __restrict__ Bp,
                                                const unsigned short* __restrict__ Ap4,
                                                const unsigned short* __restrict__ Sp5,
                                                float* __restrict__ env, int A0) {
    __shared__ unsigned short Bs_h[64 * 40];
    __shared__ unsigned short Bs_l[64 * 40];
    __shared__ unsigned short S_h[16 * 264];
    __shared__ unsigned short S_l[16 * 264];
    const int tid = threadIdx.x, lane = tid & 63, wave = tid >> 6;
    const int quad = lane >> 4, lr = lane & 15;
    const int n0 = blockIdx.x * 64;
    const int O2 = n0 >> 14, L = (n0 >> 10) & 15, a4 = (n0 >> 6) & 15;
    const int snn = tid & 63, skg = tid >> 6;

    f32x4 acc[4][4];
#pragma unroll
    for (int i = 0; i < 4; i++)
#pragma unroll
        for (int j = 0; j < 4; j++)
#pragma unroll
            for (int r = 0; r < 4; r++) acc[i][j][r] = 0.0f;

    unsigned ub[2][4];
    auto load_tile = [&](int k0) {
#pragma unroll
        for (int v = 0; v < 2; v++)
#pragma unroll
            for (int i = 0; i < 4; i++) {
                int kk = (v * 4 + skg) * 4 + i;
                ub[v][i] = Bp[(size_t)(k0 * 32 + kk) * 65536 + n0 + snn];
            }
    };
    auto store_tile = [&]() {
#pragma unroll
        for (int v = 0; v < 2; v++) {
            us4 hv, lv;
#pragma unroll
            for (int i = 0; i < 4; i++) {
                hv[i] = (unsigned short)ub[v][i];
                lv[i] = (unsigned short)(ub[v][i] >> 16);
            }
            int base = snn * 40 + (v * 4 + skg) * 4;
            *(us4*)(&Bs_h[base]) = hv;
            *(us4*)(&Bs_l[base]) = lv;
        }
    };

    load_tile(0);
    store_tile();
    for (int k0 = 0; k0 < 8; k0++) {
        __syncthreads();
        if (k0 + 1 < 8) load_tile(k0 + 1);
        bf16x8 ah[4], al[4];
#pragma unroll
        for (int mt = 0; mt < 4; mt++) {
            const unsigned short* ap =
                Ap4 + ((size_t)(k0 * 16 + wave * 4 + mt) * 2) * 512 + lane * 8;
            ah[mt] = *(const bf16x8*)ap;
            al[mt] = *(const bf16x8*)(ap + 512);
        }
#pragma unroll
        for (int nt = 0; nt < 4; nt++) {
            int nl = nt * 16 + lr;
            bf16x8 bh = *(bf16x8*)(&Bs_h[nl * 40 + quad * 8]);
            bf16x8 bl = *(bf16x8*)(&Bs_l[nl * 40 + quad * 8]);
#pragma unroll
            for (int mt = 0; mt < 4; mt++) {
                acc[mt][nt] = __builtin_amdgcn_mfma_f32_16x16x32_bf16(ah[mt], bh, acc[mt][nt], 0, 0, 0);
                acc[mt][nt] = __builtin_amdgcn_mfma_f32_16x16x32_bf16(ah[mt], bl, acc[mt][nt], 0, 0, 0);
                acc[mt][nt] = __builtin_amdgcn_mfma_f32_16x16x32_bf16(al[mt], bh, acc[mt][nt], 0, 0, 0);
            }
        }
        __syncthreads();
        if (k0 + 1 < 8) store_tile();
    }

    // phase B: per mt, deposit slab (s = wave*4+mt; k-local = wave*64+b) then
    // contract k-chunks (s2,h): global chunk = (s2*4+mt)*2+h, local = s2*64+h*32
    f32x4 acc5;
#pragma unroll
    for (int r = 0; r < 4; r++) acc5[r] = 0.0f;
#pragma unroll
    for (int mt = 0; mt < 4; mt++) {
        if (mt) __syncthreads();           // previous slab fully consumed
#pragma unroll
        for (int nt = 0; nt < 4; nt++)
#pragma unroll
            for (int r = 0; r < 4; r++) {
                unsigned u = split2(acc[mt][nt][r]);
                int addr = (quad * 4 + r) * 264 + wave * 64 + nt * 16 + lr;
                S_h[addr] = (unsigned short)u;
                S_l[addr] = (unsigned short)(u >> 16);
            }
        __syncthreads();
#pragma unroll
        for (int s2 = 0; s2 < 4; s2++)
#pragma unroll
            for (int h = 0; h < 2; h++) {
                int klocal = s2 * 64 + h * 32;
                bf16x8 th = *(const bf16x8*)(&S_h[lr * 264 + klocal + quad * 8]);
                bf16x8 tl = *(const bf16x8*)(&S_l[lr * 264 + klocal + quad * 8]);
                int kg = (s2 * 4 + mt) * 2 + h;   // global k-chunk of (s,b)
                const unsigned short* bp =
                    Sp5 + ((size_t)(kg * 4 + wave) * 2) * 512 + lane * 8;
                bf16x8 sh = *(const bf16x8*)bp;
                bf16x8 sl = *(const bf16x8*)(bp + 512);
                acc5 = __builtin_amdgcn_mfma_f32_16x16x32_bf16(th, sh, acc5, 0, 0, 0);
                acc5 = __builtin_amdgcn_mfma_f32_16x16x32_bf16(th, sl, acc5, 0, 0, 0);
                acc5 = __builtin_amdgcn_mfma_f32_16x16x32_bf16(tl, sh, acc5, 0, 0, 0);
            }
    }
    // C[row=M2=quad*4+r][col=B'=wave*16+lr] -> env[A0+a4][L,O2,M2,B'] dense
    float* dst = env + (size_t)(A0 + a4) * 65536 + L * 4096 + O2 * 1024 + wave * 16 + lr;
#pragma unroll
    for (int r = 0; r < 4; r++) dst[(quad * 4 + r) * 64] = acc5[r];
}

extern "C" void kernel_launch(void* const* d_in, const int* in_sizes, int n_in,
                              void* d_out, int out_size, void* d_ws, size_t ws_size,
                              hipStream_t stream) {
    const float* state = (const float*)d_in[0];   // [8,64,16,64]
    const float* layer = (const float*)d_in[1];   // [1,8,16,16,16,16]
    const float* oper  = (const float*)d_in[2];   // [8,4,16,16,4]
    float* out = (float*)d_out;

    const size_t need = (16777216ull + 16777216ull + 2 * 4194304ull) * 4ull +
                        (4 * 1048576ull + 65536ull) * 2ull + 4096ull;
    if (ws_size < need) {
        write_diag_kernel<<<1, 64, 0, stream>>>(out, (float)ws_size);
        return;
    }
    float* F    = (float*)d_ws;
    unsigned* P = (unsigned*)(F + 16777216);
    float* envA = (float*)(P + 16777216);
    float* envB = envA + 4194304;
    unsigned short* Ap2 = (unsigned short*)(envB + 4194304);
    unsigned short* Ap4 = Ap2 + 1048576;
    unsigned short* Sp1 = Ap4 + 1048576;
    unsigned short* Sp5 = Sp1 + 1048576;
    unsigned short* Op3 = Sp5 + 1048576;
    float* sv = (float*)(Op3 + 65536);
    float* SCR = F;

    prep_apack<<<256, 256, 0, stream>>>(layer, Ap2, Ap4);
    prep_spack1<<<256, 256, 0, stream>>>(state, Sp1);
    prep_spack5<<<256, 256, 0, stream>>>(state, Sp5);
    prep_opack3<<<16, 256, 0, stream>>>(oper, Op3);
    prep_sv<<<4, 256, 0, stream>>>(state, sv);

    // site 0 -> envB (exact fp32), env row-major [a][n]
    s0_g2<<<64, 256, 0, stream>>>(state, layer, SCR);
    s0_g3<<<256, 256, 0, stream>>>(SCR, oper, SCR + 16384);
    s0_g4<<<4096, 256, 0, stream>>>(SCR + 16384, layer, SCR + 81920);
    s0_env<<<16384, 256, 0, stream>>>(SCR + 81920, state, envB);

    for (int q = 1; q < 7; q++) {
        float* ein  = (q & 1) ? envB : envA;
        float* eout = (q & 1) ? envA : envB;
        for (int c = 0; c < 4; c++) {
            gemm_u<2, 16, 0, 1, 1><<<1024, 256, 0, stream>>>(
                ein, Sp1 + (size_t)(q * 4 + c) * 32768, nullptr, P, 65536);
            gemm_u<8, 16, 0, 0, 2><<<1024, 256, 0, stream>>>(
                P, Ap2 + (size_t)q * 131072, F, nullptr, 65536);
            gemm_u<2, 4, 1, 1, 3><<<4096, 256, 0, stream>>>(
                F, Op3 + (size_t)q * 8192, nullptr, P, 262144);
            gemm_g45<<<1024, 256, 0, stream>>>(
                P, Ap4 + (size_t)q * 131072, Sp5 + (size_t)q * 131072, eout, c * 16);
        }
    }

    // site 7: out = <env7 (row-major, in envB), w>
    s7_c1<<<64, 256, 0, stream>>>(state, layer, SCR);
    s7_c2<<<256, 256, 0, stream>>>(SCR, oper, SCR + 16384);
    s7_c3<<<4096, 256, 0, stream>>>(SCR + 16384, layer, SCR + 81920);
    zero_out<<<1, 64, 0, stream>>>(out);
    s7_fused<<<1024, 256, 0, stream>>>(envB, SCR + 81920, sv, out);
}